// Round 7
// baseline (281.009 us; speedup 1.0000x reference)
//
#include <hip/hip_runtime.h>
#include <cstdint>

#define NNODES 50000
#define NEDGES 800000
#define NEG 0.2f
#define NB 196          // ceil(50000/256) scan blocks

__device__ __forceinline__ float leaky(float v) { return v > 0.f ? v : NEG * v; }

__device__ __forceinline__ unsigned short f2bf(float f) {   // round-to-nearest-even
    unsigned int u = __float_as_uint(f);
    u += 0x7fff + ((u >> 16) & 1);
    return (unsigned short)(u >> 16);
}

// K1: h = x @ W  [50000,128]x[128,128] fp32 compute; h stored bf16; logits fused.
__global__ __launch_bounds__(256) void gemm_k(const float* __restrict__ x,
                                              const float* __restrict__ W,
                                              unsigned short* __restrict__ hb,
                                              const float* __restrict__ att_src,
                                              const float* __restrict__ att_dst,
                                              float* __restrict__ a_src,
                                              float* __restrict__ a_dst) {
    __shared__ float xs[32][128];
    const int tid = threadIdx.x;
    const int rbase = blockIdx.x * 32;
    #pragma unroll
    for (int i = 0; i < 16; ++i) {
        int idx = tid + i * 256;
        int r = idx >> 7, k = idx & 127;
        int gr = rbase + r;
        xs[r][k] = (gr < NNODES) ? x[(size_t)gr * 128 + k] : 0.f;
    }
    __syncthreads();
    const int cp = tid & 63;
    const int rg = tid >> 6;
    float acc0[8], acc1[8];
    #pragma unroll
    for (int r = 0; r < 8; ++r) { acc0[r] = 0.f; acc1[r] = 0.f; }
    const float2* W2 = (const float2*)W;
    for (int k = 0; k < 128; k += 4) {
        float2 w0 = W2[(k + 0) * 64 + cp];
        float2 w1 = W2[(k + 1) * 64 + cp];
        float2 w2 = W2[(k + 2) * 64 + cp];
        float2 w3 = W2[(k + 3) * 64 + cp];
        #pragma unroll
        for (int r = 0; r < 8; ++r) {
            float4 xv = *(const float4*)&xs[rg * 8 + r][k];  // wave-uniform -> LDS broadcast
            acc0[r] += xv.x * w0.x; acc1[r] += xv.x * w0.y;
            acc0[r] += xv.y * w1.x; acc1[r] += xv.y * w1.y;
            acc0[r] += xv.z * w2.x; acc1[r] += xv.z * w2.y;
            acc0[r] += xv.w * w3.x; acc1[r] += xv.w * w3.y;
        }
    }
    // epilogue: bf16 store + fused per-(row,head) logits
    float2 as_v = ((const float2*)att_src)[cp];
    float2 ad_v = ((const float2*)att_dst)[cp];
    #pragma unroll
    for (int r = 0; r < 8; ++r) {
        int row = rbase + rg * 8 + r;
        ushort2 hs;
        hs.x = f2bf(acc0[r]); hs.y = f2bf(acc1[r]);
        if (row < NNODES) ((ushort2*)(hb + (size_t)row * 128))[cp] = hs;
        float ps = acc0[r] * as_v.x + acc1[r] * as_v.y;
        float pd = acc0[r] * ad_v.x + acc1[r] * ad_v.y;
        #pragma unroll
        for (int m = 8; m >= 1; m >>= 1) {
            ps += __shfl_xor(ps, m, 16);
            pd += __shfl_xor(pd, m, 16);
        }
        if (row < NNODES && (cp & 15) == 0) {
            a_src[row * 4 + (cp >> 4)] = ps;
            a_dst[row * 4 + (cp >> 4)] = pd;
        }
    }
}

// K3: histogram of dst degrees (deg pre-zeroed by hipMemsetAsync)
__global__ __launch_bounds__(256) void hist_k(const int* __restrict__ ei,
                                              int* __restrict__ deg) {
    const int e = blockIdx.x * 256 + threadIdx.x;
    if (e >= NEDGES) return;
    atomicAdd(&deg[ei[NEDGES + e]], 1);
}

// ---- multi-block exclusive scan of deg[50000] -> off/cur ----
__device__ __forceinline__ int block_excl_scan(int v, int t) {
    __shared__ int wsum[4];
    const int lane = t & 63, wv = t >> 6;
    int x = v;
    #pragma unroll
    for (int m = 1; m < 64; m <<= 1) {
        int u = __shfl_up(x, m);
        if (lane >= m) x += u;
    }
    if (lane == 63) wsum[wv] = x;
    __syncthreads();
    if (t == 0) {
        int run = 0;
        #pragma unroll
        for (int i = 0; i < 4; ++i) { int tmp = wsum[i]; wsum[i] = run; run += tmp; }
    }
    __syncthreads();
    return x - v + wsum[wv];
}

__global__ __launch_bounds__(256) void scanA_k(const int* __restrict__ deg,
                                               int* __restrict__ off,
                                               int* __restrict__ bsum) {
    const int b = blockIdx.x, t = threadIdx.x;
    const int i = b * 256 + t;
    int v = (i < NNODES) ? deg[i] : 0;
    int excl = block_excl_scan(v, t);
    if (i < NNODES) off[i] = excl;
    if (t == 255) bsum[b] = excl + v;
}

__global__ __launch_bounds__(256) void scanB_k(int* __restrict__ bsum,
                                               int* __restrict__ bofs) {
    const int t = threadIdx.x;
    int v = (t < NB) ? bsum[t] : 0;
    int excl = block_excl_scan(v, t);
    if (t < NB) bofs[t] = excl;
}

__global__ __launch_bounds__(256) void scanC_k(int* __restrict__ off,
                                               const int* __restrict__ bofs,
                                               int* __restrict__ cur) {
    const int b = blockIdx.x, t = threadIdx.x;
    const int i = b * 256 + t;
    if (i < NNODES) {
        int o = off[i] + bofs[b];
        off[i] = o;
        cur[i] = o;
    }
    if (b == 0 && t == 0) off[NNODES] = NEDGES;
}

// K5: counting-sort fill. csr written via atomicExch -> executes memory-side
// (MALL), avoiding the 64B/4B partial-line write-through to HBM (was 52MB
// WRITE_SIZE for a 3.2MB array).
__global__ __launch_bounds__(256) void fill_k(const int* __restrict__ ei,
                                              int* __restrict__ cur,
                                              int* __restrict__ csr) {
    const int e = blockIdx.x * 256 + threadIdx.x;
    if (e >= NEDGES) return;
    const int s = ei[e];
    const int d = ei[NEDGES + e];
    int pos = atomicAdd(&cur[d], 1);
    atomicExch(&csr[pos], s);
}

// K6: gather per dst node from bf16 h: out[n] = (w_self*h[n] + sum w_j*h[s_j])/denom + bias
__global__ __launch_bounds__(256) void gather_k(const int* __restrict__ off,
                                                const int* __restrict__ csr,
                                                const unsigned short* __restrict__ hb,
                                                const float* __restrict__ a_src,
                                                const float* __restrict__ a_dst,
                                                const float* __restrict__ bias,
                                                float* __restrict__ out) {
    const int wid = threadIdx.x >> 6, lane = threadIdx.x & 63;
    const int n = blockIdx.x * 4 + wid;
    if (n >= NNODES) return;
    const int head = lane >> 4;
    const int sub = lane & 15;

    const float a_d = a_dst[n * 4 + head];
    const float w_self = __expf(leaky(a_src[n * 4 + head] + a_d));
    unsigned int hv0 = ((const unsigned int*)(hb + (size_t)n * 128))[lane];
    float hnx = __uint_as_float(hv0 << 16);
    float hny = __uint_as_float(hv0 & 0xffff0000u);
    float accx = w_self * hnx, accy = w_self * hny;
    float denom = w_self;

    const int beg = off[n], end = off[n + 1];
    for (int base = beg; base < end; base += 16) {
        int m = end - base; if (m > 16) m = 16;
        int s = 0;
        float w = 0.f;
        if (sub < m) {
            s = csr[base + sub];
            w = __expf(leaky(a_src[s * 4 + head] + a_d));
        }
        if (m == 16) {
            #pragma unroll
            for (int j = 0; j < 16; ++j) {
                int   sj = __shfl(s, j);
                float wj = __shfl(w, (head << 4) | j);
                unsigned int hv = ((const unsigned int*)(hb + (size_t)sj * 128))[lane];
                float hx = __uint_as_float(hv << 16);
                float hy = __uint_as_float(hv & 0xffff0000u);
                denom += wj;
                accx += wj * hx; accy += wj * hy;
            }
        } else {
            for (int j = 0; j < m; ++j) {
                int   sj = __shfl(s, j);
                float wj = __shfl(w, (head << 4) | j);
                unsigned int hv = ((const unsigned int*)(hb + (size_t)sj * 128))[lane];
                float hx = __uint_as_float(hv << 16);
                float hy = __uint_as_float(hv & 0xffff0000u);
                denom += wj;
                accx += wj * hx; accy += wj * hy;
            }
        }
    }
    const float inv = __frcp_rn(denom);
    float2 bv = ((const float2*)bias)[lane];
    ((float2*)(out + (size_t)n * 128))[lane] =
        make_float2(accx * inv + bv.x, accy * inv + bv.y);
}

extern "C" void kernel_launch(void* const* d_in, const int* in_sizes, int n_in,
                              void* d_out, int out_size, void* d_ws, size_t ws_size,
                              hipStream_t stream) {
    const float* x     = (const float*)d_in[0];
    const int*   ei    = (const int*)d_in[1];   // int64 ref -> delivered int32
    const float* W     = (const float*)d_in[2];
    const float* att_s = (const float*)d_in[3];
    const float* att_d = (const float*)d_in[4];
    const float* bias  = (const float*)d_in[5];
    float*       out   = (float*)d_out;
    char*        ws    = (char*)d_ws;

    // ws layout (bytes):
    // hb (bf16) 12.8MB | a_src 0.8MB | a_dst 0.8MB | deg 200KB | off 200KB+4 | cur 200KB | csr 3.2MB | bsum | bofs
    unsigned short* hb  = (unsigned short*)(ws);
    float* a_src = (float*)(ws + 12800000);
    float* a_dst = (float*)(ws + 13600000);
    int*   deg   = (int*)  (ws + 14400000);
    int*   off   = (int*)  (ws + 14600000);
    int*   cur   = (int*)  (ws + 14800064);
    int*   csr   = (int*)  (ws + 15000064);
    int*   bsum  = (int*)  (ws + 18200064);
    int*   bofs  = (int*)  (ws + 18201088);

    hipMemsetAsync(deg, 0, NNODES * sizeof(int), stream);
    gemm_k   <<<1563,  256, 0, stream>>>(x, W, hb, att_s, att_d, a_src, a_dst);
    hist_k   <<<3125,  256, 0, stream>>>(ei, deg);
    scanA_k  <<<NB,    256, 0, stream>>>(deg, off, bsum);
    scanB_k  <<<1,     256, 0, stream>>>(bsum, bofs);
    scanC_k  <<<NB,    256, 0, stream>>>(off, bofs, cur);
    fill_k   <<<3125,  256, 0, stream>>>(ei, cur, csr);
    gather_k <<<12500, 256, 0, stream>>>(off, csr, hb, a_src, a_dst, bias, out);
}

// Round 8
// 188.765 us; speedup vs baseline: 1.4887x; 1.4887x over previous
//
#include <hip/hip_runtime.h>
#include <cstdint>

#define NNODES 50000
#define NEDGES 800000
#define NEG 0.2f
#define NBKT 196        // buckets of 256 nodes: 196*256 = 50176 >= 50000
#define BCAP 5120       // per-bucket capacity (mean 4082, sd 64 -> 16 sigma headroom)

__device__ __forceinline__ float leaky(float v) { return v > 0.f ? v : NEG * v; }

__device__ __forceinline__ unsigned short f2bf(float f) {   // round-to-nearest-even
    unsigned int u = __float_as_uint(f);
    u += 0x7fff + ((u >> 16) & 1);
    return (unsigned short)(u >> 16);
}

// 256-thread block exclusive scan (shfl within wave + LDS across 4 waves)
__device__ __forceinline__ int block_excl_scan(int v, int t) {
    __shared__ int wsum[4];
    const int lane = t & 63, wv = t >> 6;
    int x = v;
    #pragma unroll
    for (int m = 1; m < 64; m <<= 1) {
        int u = __shfl_up(x, m);
        if (lane >= m) x += u;
    }
    if (lane == 63) wsum[wv] = x;
    __syncthreads();
    if (t == 0) {
        int run = 0;
        #pragma unroll
        for (int i = 0; i < 4; ++i) { int tmp = wsum[i]; wsum[i] = run; run += tmp; }
    }
    __syncthreads();
    return x - v + wsum[wv];
}

// K1: h = x @ W  [50000,128]x[128,128] fp32 compute; h stored bf16; logits fused.
__global__ __launch_bounds__(256) void gemm_k(const float* __restrict__ x,
                                              const float* __restrict__ W,
                                              unsigned short* __restrict__ hb,
                                              const float* __restrict__ att_src,
                                              const float* __restrict__ att_dst,
                                              float* __restrict__ a_src,
                                              float* __restrict__ a_dst) {
    __shared__ float xs[32][128];
    const int tid = threadIdx.x;
    const int rbase = blockIdx.x * 32;
    #pragma unroll
    for (int i = 0; i < 16; ++i) {
        int idx = tid + i * 256;
        int r = idx >> 7, k = idx & 127;
        int gr = rbase + r;
        xs[r][k] = (gr < NNODES) ? x[(size_t)gr * 128 + k] : 0.f;
    }
    __syncthreads();
    const int cp = tid & 63;
    const int rg = tid >> 6;
    float acc0[8], acc1[8];
    #pragma unroll
    for (int r = 0; r < 8; ++r) { acc0[r] = 0.f; acc1[r] = 0.f; }
    const float2* W2 = (const float2*)W;
    for (int k = 0; k < 128; k += 4) {
        float2 w0 = W2[(k + 0) * 64 + cp];
        float2 w1 = W2[(k + 1) * 64 + cp];
        float2 w2 = W2[(k + 2) * 64 + cp];
        float2 w3 = W2[(k + 3) * 64 + cp];
        #pragma unroll
        for (int r = 0; r < 8; ++r) {
            float4 xv = *(const float4*)&xs[rg * 8 + r][k];  // wave-uniform -> LDS broadcast
            acc0[r] += xv.x * w0.x; acc1[r] += xv.x * w0.y;
            acc0[r] += xv.y * w1.x; acc1[r] += xv.y * w1.y;
            acc0[r] += xv.z * w2.x; acc1[r] += xv.z * w2.y;
            acc0[r] += xv.w * w3.x; acc1[r] += xv.w * w3.y;
        }
    }
    float2 as_v = ((const float2*)att_src)[cp];
    float2 ad_v = ((const float2*)att_dst)[cp];
    #pragma unroll
    for (int r = 0; r < 8; ++r) {
        int row = rbase + rg * 8 + r;
        ushort2 hs;
        hs.x = f2bf(acc0[r]); hs.y = f2bf(acc1[r]);
        if (row < NNODES) ((ushort2*)(hb + (size_t)row * 128))[cp] = hs;
        float ps = acc0[r] * as_v.x + acc1[r] * as_v.y;
        float pd = acc0[r] * ad_v.x + acc1[r] * ad_v.y;
        #pragma unroll
        for (int m = 8; m >= 1; m >>= 1) {
            ps += __shfl_xor(ps, m, 16);
            pd += __shfl_xor(pd, m, 16);
        }
        if (row < NNODES && (cp & 15) == 0) {
            a_src[row * 4 + (cp >> 4)] = ps;
            a_dst[row * 4 + (cp >> 4)] = pd;
        }
    }
}

// K2: bin edges by dst>>8 into per-bucket global regions, LDS-staged so each
// bucket's run is written contiguously by this block (full-line writes).
// Entry pack: (bucket<<24) | (dst&255)<<16 | src   (src<50000<2^16).
__global__ __launch_bounds__(256) void bin_k(const int* __restrict__ ei,
                                             int* __restrict__ bcnt,
                                             unsigned int* __restrict__ bktdata) {
    __shared__ int lhist[NBKT];
    __shared__ int lofs[NBKT];
    __shared__ int lcur[NBKT];
    __shared__ int gbase[NBKT];
    __shared__ unsigned int staged[4096];
    const int b = blockIdx.x, t = threadIdx.x;
    for (int i = t; i < NBKT; i += 256) lhist[i] = 0;
    __syncthreads();
    unsigned int pk[16];
    int bk[16];
    const int e0 = b * 4096;
    #pragma unroll
    for (int i = 0; i < 16; ++i) {
        int e = e0 + i * 256 + t;
        if (e < NEDGES) {
            int s = ei[e], d = ei[NEDGES + e];
            bk[i] = d >> 8;
            pk[i] = ((unsigned)bk[i] << 24) | ((unsigned)(d & 255) << 16) | (unsigned)s;
            atomicAdd(&lhist[bk[i]], 1);
        } else bk[i] = -1;
    }
    __syncthreads();
    int v = (t < NBKT) ? lhist[t] : 0;
    int excl = block_excl_scan(v, t);
    if (t < NBKT) { lofs[t] = excl; lcur[t] = excl; }
    __syncthreads();
    if (t < NBKT) gbase[t] = (v > 0) ? atomicAdd(&bcnt[t], v) : 0;
    #pragma unroll
    for (int i = 0; i < 16; ++i) {
        if (bk[i] >= 0) {
            int pos = atomicAdd(&lcur[bk[i]], 1);
            staged[pos] = pk[i];
        }
    }
    __syncthreads();
    const int total = lofs[NBKT - 1] + lhist[NBKT - 1];
    for (int i = t; i < total; i += 256) {
        unsigned int ent = staged[i];
        int bb = ent >> 24;
        int pos = gbase[bb] + (i - lofs[bb]);
        bktdata[(size_t)bb * BCAP + pos] = ent & 0xFFFFFFu >> 8 ? (ent & 0x00FFFFFFu) : (ent & 0x00FFFFFFu);
    }
}

// K3: scan the 196 bucket totals -> csr base per bucket
__global__ __launch_bounds__(256) void bscan_k(const int* __restrict__ bcnt,
                                               int* __restrict__ bktoff) {
    const int t = threadIdx.x;
    int v = (t < NBKT) ? bcnt[t] : 0;
    int excl = block_excl_scan(v, t);
    if (t < NBKT) bktoff[t] = excl;
}

// K4: per-bucket counting sort in LDS; writes off (coalesced) + csr (coalesced).
__global__ __launch_bounds__(256) void sort_k(const int* __restrict__ bcnt,
                                              const int* __restrict__ bktoff,
                                              const unsigned int* __restrict__ bktdata,
                                              int* __restrict__ off,
                                              int* __restrict__ csr) {
    __shared__ unsigned int staged[BCAP];
    __shared__ int sorted[BCAP];
    __shared__ int lcnt[256];
    __shared__ int lcur[256];
    const int b = blockIdx.x, t = threadIdx.x;
    const int cnt = bcnt[b], base = bktoff[b];
    lcnt[t] = 0;
    for (int i = t; i < cnt; i += 256) staged[i] = bktdata[(size_t)b * BCAP + i];
    __syncthreads();
    for (int i = t; i < cnt; i += 256) atomicAdd(&lcnt[staged[i] >> 16], 1);
    __syncthreads();
    int v = lcnt[t];
    int excl = block_excl_scan(v, t);
    lcur[t] = excl;
    const int node = b * 256 + t;
    if (node <= NNODES) off[node] = base + excl;
    __syncthreads();
    for (int i = t; i < cnt; i += 256) {
        unsigned int ent = staged[i];
        int pos = atomicAdd(&lcur[ent >> 16], 1);
        sorted[pos] = (int)(ent & 0xFFFFu);
    }
    __syncthreads();
    for (int i = t; i < cnt; i += 256) csr[base + i] = sorted[i];
}

// K5: gather per dst node from bf16 h: out[n] = (w_self*h[n] + sum w_j*h[s_j])/denom + bias
__global__ __launch_bounds__(256) void gather_k(const int* __restrict__ off,
                                                const int* __restrict__ csr,
                                                const unsigned short* __restrict__ hb,
                                                const float* __restrict__ a_src,
                                                const float* __restrict__ a_dst,
                                                const float* __restrict__ bias,
                                                float* __restrict__ out) {
    const int wid = threadIdx.x >> 6, lane = threadIdx.x & 63;
    const int n = blockIdx.x * 4 + wid;
    if (n >= NNODES) return;
    const int head = lane >> 4;
    const int sub = lane & 15;

    const float a_d = a_dst[n * 4 + head];
    const float w_self = __expf(leaky(a_src[n * 4 + head] + a_d));
    unsigned int hv0 = ((const unsigned int*)(hb + (size_t)n * 128))[lane];
    float hnx = __uint_as_float(hv0 << 16);
    float hny = __uint_as_float(hv0 & 0xffff0000u);
    float accx = w_self * hnx, accy = w_self * hny;
    float denom = w_self;

    const int beg = off[n], end = off[n + 1];
    for (int base = beg; base < end; base += 16) {
        int m = end - base; if (m > 16) m = 16;
        int s = 0;
        float w = 0.f;
        if (sub < m) {
            s = csr[base + sub];
            w = __expf(leaky(a_src[s * 4 + head] + a_d));
        }
        if (m == 16) {
            #pragma unroll
            for (int j = 0; j < 16; ++j) {
                int   sj = __shfl(s, j);
                float wj = __shfl(w, (head << 4) | j);
                unsigned int hv = ((const unsigned int*)(hb + (size_t)sj * 128))[lane];
                float hx = __uint_as_float(hv << 16);
                float hy = __uint_as_float(hv & 0xffff0000u);
                denom += wj;
                accx += wj * hx; accy += wj * hy;
            }
        } else {
            for (int j = 0; j < m; ++j) {
                int   sj = __shfl(s, j);
                float wj = __shfl(w, (head << 4) | j);
                unsigned int hv = ((const unsigned int*)(hb + (size_t)sj * 128))[lane];
                float hx = __uint_as_float(hv << 16);
                float hy = __uint_as_float(hv & 0xffff0000u);
                denom += wj;
                accx += wj * hx; accy += wj * hy;
            }
        }
    }
    const float inv = __frcp_rn(denom);
    float2 bv = ((const float2*)bias)[lane];
    ((float2*)(out + (size_t)n * 128))[lane] =
        make_float2(accx * inv + bv.x, accy * inv + bv.y);
}

extern "C" void kernel_launch(void* const* d_in, const int* in_sizes, int n_in,
                              void* d_out, int out_size, void* d_ws, size_t ws_size,
                              hipStream_t stream) {
    const float* x     = (const float*)d_in[0];
    const int*   ei    = (const int*)d_in[1];   // int64 ref -> delivered int32
    const float* W     = (const float*)d_in[2];
    const float* att_s = (const float*)d_in[3];
    const float* att_d = (const float*)d_in[4];
    const float* bias  = (const float*)d_in[5];
    float*       out   = (float*)d_out;
    char*        ws    = (char*)d_ws;

    // ws layout (bytes):
    // hb (bf16) 12.8MB | a_src 0.8MB | a_dst 0.8MB | off 50177*4 | csr 3.2MB |
    // bktdata 196*5120*4 = 4.01MB | bcnt 784B | bktoff 784B
    unsigned short* hb = (unsigned short*)(ws);
    float* a_src  = (float*)(ws + 12800000);
    float* a_dst  = (float*)(ws + 13600000);
    int*   off    = (int*)  (ws + 14400000);
    int*   csr    = (int*)  (ws + 14600768);
    unsigned int* bktdata = (unsigned int*)(ws + 17800768);
    int*   bcnt   = (int*)  (ws + 21814848);
    int*   bktoff = (int*)  (ws + 21815680);

    hipMemsetAsync(bcnt, 0, NBKT * sizeof(int), stream);
    gemm_k  <<<1563,  256, 0, stream>>>(x, W, hb, att_s, att_d, a_src, a_dst);
    bin_k   <<<196,   256, 0, stream>>>(ei, bcnt, bktdata);
    bscan_k <<<1,     256, 0, stream>>>(bcnt, bktoff);
    sort_k  <<<196,   256, 0, stream>>>(bcnt, bktoff, bktdata, off, csr);
    gather_k<<<12500, 256, 0, stream>>>(off, csr, hb, a_src, a_dst, bias, out);
}

// Round 9
// 169.168 us; speedup vs baseline: 1.6611x; 1.1158x over previous
//
#include <hip/hip_runtime.h>
#include <cstdint>

#define NNODES 50000
#define NEDGES 800000
#define NEG 0.2f
#define NBKT 196        // buckets of 256 nodes: 196*256 = 50176 >= 50000
#define BCAP 5120       // per-bucket capacity (mean 4082, sd 64 -> 16 sigma headroom)

typedef __attribute__((ext_vector_type(8))) short short8;   // 8 bf16 (4 VGPRs)
typedef __attribute__((ext_vector_type(4))) float f32x4;

#define AS_STRIDE 136   // ushorts; 272B rows -> 16B aligned
#define CS_STRIDE 132   // floats; breaks 128-mod-32 bank aliasing

__device__ __forceinline__ float leaky(float v) { return v > 0.f ? v : NEG * v; }

__device__ __forceinline__ unsigned short f2bf(float f) {   // round-to-nearest-even
    unsigned int u = __float_as_uint(f);
    u += 0x7fff + ((u >> 16) & 1);
    return (unsigned short)(u >> 16);
}

// 256-thread block exclusive scan (shfl within wave + LDS across 4 waves)
__device__ __forceinline__ int block_excl_scan(int v, int t) {
    __shared__ int wsum[4];
    const int lane = t & 63, wv = t >> 6;
    int x = v;
    #pragma unroll
    for (int m = 1; m < 64; m <<= 1) {
        int u = __shfl_up(x, m);
        if (lane >= m) x += u;
    }
    if (lane == 63) wsum[wv] = x;
    __syncthreads();
    if (t == 0) {
        int run = 0;
        #pragma unroll
        for (int i = 0; i < 4; ++i) { int tmp = wsum[i]; wsum[i] = run; run += tmp; }
    }
    __syncthreads();
    return x - v + wsum[wv];
}

// K1: h = x @ W via bf16 MFMA. Block: 64 rows x 128 cols, K=128 one pass.
// 4 waves; wave w owns rows w*16..w*16+15 (one m-tile), all 8 n-tiles.
// Epilogue stages C in LDS (aliases A/B), then bf16-pack h + fused logits.
__global__ __launch_bounds__(256) void gemm_k(const float* __restrict__ x,
                                              const float* __restrict__ W,
                                              unsigned short* __restrict__ hb,
                                              const float* __restrict__ att_src,
                                              const float* __restrict__ att_dst,
                                              float* __restrict__ a_src,
                                              float* __restrict__ a_dst) {
    __shared__ __align__(16) char smem[52224];
    unsigned short* As = (unsigned short*)smem;            // [64][AS_STRIDE] bf16
    unsigned short* Bs = (unsigned short*)(smem + 17408);  // WT [128][AS_STRIDE] bf16
    float*          Cs = (float*)smem;                     // [64][CS_STRIDE] fp32 (aliases)

    const int tid = threadIdx.x;
    const int rbase = blockIdx.x * 64;

    // stage A: x[rbase..rbase+63][0..127] fp32 -> bf16 LDS
    #pragma unroll
    for (int i = 0; i < 8; ++i) {
        int f = tid + i * 256;           // float4 index; 32 per row
        int r = f >> 5, c4 = (f & 31) * 4;
        float4 xv = make_float4(0.f, 0.f, 0.f, 0.f);
        if (rbase + r < NNODES) xv = ((const float4*)x)[(size_t)(rbase + r) * 32 + (f & 31)];
        unsigned int p0 = ((unsigned int)f2bf(xv.y) << 16) | f2bf(xv.x);
        unsigned int p1 = ((unsigned int)f2bf(xv.w) << 16) | f2bf(xv.z);
        *(uint2*)(As + r * AS_STRIDE + c4) = make_uint2(p0, p1);
    }
    // stage B: W[k][n] fp32 -> WT[n][k] bf16 LDS
    #pragma unroll
    for (int i = 0; i < 64; ++i) {
        int f = tid + i * 256;
        int k = f >> 7, n = f & 127;
        Bs[n * AS_STRIDE + k] = f2bf(W[f]);
    }
    __syncthreads();

    const int lane = tid & 63, w = tid >> 6;
    const int quad = lane >> 4, m16 = lane & 15;

    short8 af[4];
    #pragma unroll
    for (int s = 0; s < 4; ++s)
        af[s] = *(const short8*)(As + (w * 16 + m16) * AS_STRIDE + s * 32 + quad * 8);

    f32x4 acc[8];
    #pragma unroll
    for (int t = 0; t < 8; ++t) acc[t] = (f32x4){0.f, 0.f, 0.f, 0.f};

    #pragma unroll
    for (int t = 0; t < 8; ++t) {
        #pragma unroll
        for (int s = 0; s < 4; ++s) {
            short8 bf = *(const short8*)(Bs + (t * 16 + m16) * AS_STRIDE + s * 32 + quad * 8);
            acc[t] = __builtin_amdgcn_mfma_f32_16x16x32_bf16(af[s], bf, acc[t], 0, 0, 0);
        }
    }
    __syncthreads();   // done reading As/Bs; safe to alias with Cs

    // C layout: col = lane&15 (within tile), row = quad*4 + reg
    #pragma unroll
    for (int t = 0; t < 8; ++t)
        #pragma unroll
        for (int r = 0; r < 4; ++r)
            Cs[(w * 16 + quad * 4 + r) * CS_STRIDE + t * 16 + m16] = acc[t][r];
    __syncthreads();

    // epilogue: bf16 store + fused logits. lane cp = col pair (cols 2cp,2cp+1)
    const int cp = lane;
    float2 as_v = ((const float2*)att_src)[cp];
    float2 ad_v = ((const float2*)att_dst)[cp];
    #pragma unroll
    for (int r = 0; r < 16; ++r) {
        int row = w * 16 + r;
        int row_g = rbase + row;
        float2 cv = *(const float2*)(Cs + row * CS_STRIDE + 2 * cp);
        ushort2 hs;
        hs.x = f2bf(cv.x); hs.y = f2bf(cv.y);
        if (row_g < NNODES) ((ushort2*)(hb + (size_t)row_g * 128))[cp] = hs;
        float ps = cv.x * as_v.x + cv.y * as_v.y;
        float pd = cv.x * ad_v.x + cv.y * ad_v.y;
        #pragma unroll
        for (int m = 8; m >= 1; m >>= 1) {
            ps += __shfl_xor(ps, m, 16);
            pd += __shfl_xor(pd, m, 16);
        }
        if (row_g < NNODES && (cp & 15) == 0) {
            a_src[row_g * 4 + (cp >> 4)] = ps;
            a_dst[row_g * 4 + (cp >> 4)] = pd;
        }
    }
}

// K2: bin edges by dst>>8 into per-bucket global regions, LDS-staged so each
// bucket's run is written contiguously by this block (full-line writes).
// Entry pack: (bucket<<24) | (dst&255)<<16 | src   (src<50000<2^16).
__global__ __launch_bounds__(256) void bin_k(const int* __restrict__ ei,
                                             int* __restrict__ bcnt,
                                             unsigned int* __restrict__ bktdata) {
    __shared__ int lhist[NBKT];
    __shared__ int lofs[NBKT];
    __shared__ int lcur[NBKT];
    __shared__ int gbase[NBKT];
    __shared__ unsigned int staged[4096];
    const int b = blockIdx.x, t = threadIdx.x;
    for (int i = t; i < NBKT; i += 256) lhist[i] = 0;
    __syncthreads();
    unsigned int pk[16];
    int bk[16];
    const int e0 = b * 4096;
    #pragma unroll
    for (int i = 0; i < 16; ++i) {
        int e = e0 + i * 256 + t;
        if (e < NEDGES) {
            int s = ei[e], d = ei[NEDGES + e];
            bk[i] = d >> 8;
            pk[i] = ((unsigned)bk[i] << 24) | ((unsigned)(d & 255) << 16) | (unsigned)s;
            atomicAdd(&lhist[bk[i]], 1);
        } else bk[i] = -1;
    }
    __syncthreads();
    int v = (t < NBKT) ? lhist[t] : 0;
    int excl = block_excl_scan(v, t);
    if (t < NBKT) { lofs[t] = excl; lcur[t] = excl; }
    __syncthreads();
    if (t < NBKT) gbase[t] = (v > 0) ? atomicAdd(&bcnt[t], v) : 0;
    #pragma unroll
    for (int i = 0; i < 16; ++i) {
        if (bk[i] >= 0) {
            int pos = atomicAdd(&lcur[bk[i]], 1);
            staged[pos] = pk[i];
        }
    }
    __syncthreads();
    const int total = lofs[NBKT - 1] + lhist[NBKT - 1];
    for (int i = t; i < total; i += 256) {
        unsigned int ent = staged[i];
        int bb = ent >> 24;
        int pos = gbase[bb] + (i - lofs[bb]);
        bktdata[(size_t)bb * BCAP + pos] = ent & 0x00FFFFFFu;
    }
}

// K3: scan the 196 bucket totals -> csr base per bucket
__global__ __launch_bounds__(256) void bscan_k(const int* __restrict__ bcnt,
                                               int* __restrict__ bktoff) {
    const int t = threadIdx.x;
    int v = (t < NBKT) ? bcnt[t] : 0;
    int excl = block_excl_scan(v, t);
    if (t < NBKT) bktoff[t] = excl;
}

// K4: per-bucket counting sort in LDS; writes off (coalesced) + csr (coalesced).
__global__ __launch_bounds__(256) void sort_k(const int* __restrict__ bcnt,
                                              const int* __restrict__ bktoff,
                                              const unsigned int* __restrict__ bktdata,
                                              int* __restrict__ off,
                                              int* __restrict__ csr) {
    __shared__ unsigned int staged[BCAP];
    __shared__ int sorted[BCAP];
    __shared__ int lcnt[256];
    __shared__ int lcur[256];
    const int b = blockIdx.x, t = threadIdx.x;
    const int cnt = bcnt[b], base = bktoff[b];
    lcnt[t] = 0;
    for (int i = t; i < cnt; i += 256) staged[i] = bktdata[(size_t)b * BCAP + i];
    __syncthreads();
    for (int i = t; i < cnt; i += 256) atomicAdd(&lcnt[staged[i] >> 16], 1);
    __syncthreads();
    int v = lcnt[t];
    int excl = block_excl_scan(v, t);
    lcur[t] = excl;
    const int node = b * 256 + t;
    if (node <= NNODES) off[node] = base + excl;
    __syncthreads();
    for (int i = t; i < cnt; i += 256) {
        unsigned int ent = staged[i];
        int pos = atomicAdd(&lcur[ent >> 16], 1);
        sorted[pos] = (int)(ent & 0xFFFFu);
    }
    __syncthreads();
    for (int i = t; i < cnt; i += 256) csr[base + i] = sorted[i];
}

// K5: gather per dst node from bf16 h: out[n] = (w_self*h[n] + sum w_j*h[s_j])/denom + bias
__global__ __launch_bounds__(256) void gather_k(const int* __restrict__ off,
                                                const int* __restrict__ csr,
                                                const unsigned short* __restrict__ hb,
                                                const float* __restrict__ a_src,
                                                const float* __restrict__ a_dst,
                                                const float* __restrict__ bias,
                                                float* __restrict__ out) {
    const int wid = threadIdx.x >> 6, lane = threadIdx.x & 63;
    const int n = blockIdx.x * 4 + wid;
    if (n >= NNODES) return;
    const int head = lane >> 4;
    const int sub = lane & 15;

    const float a_d = a_dst[n * 4 + head];
    const float w_self = __expf(leaky(a_src[n * 4 + head] + a_d));
    unsigned int hv0 = ((const unsigned int*)(hb + (size_t)n * 128))[lane];
    float hnx = __uint_as_float(hv0 << 16);
    float hny = __uint_as_float(hv0 & 0xffff0000u);
    float accx = w_self * hnx, accy = w_self * hny;
    float denom = w_self;

    const int beg = off[n], end = off[n + 1];
    for (int base = beg; base < end; base += 16) {
        int m = end - base; if (m > 16) m = 16;
        int s = 0;
        float w = 0.f;
        if (sub < m) {
            s = csr[base + sub];
            w = __expf(leaky(a_src[s * 4 + head] + a_d));
        }
        if (m == 16) {
            #pragma unroll
            for (int j = 0; j < 16; ++j) {
                int   sj = __shfl(s, j);
                float wj = __shfl(w, (head << 4) | j);
                unsigned int hv = ((const unsigned int*)(hb + (size_t)sj * 128))[lane];
                float hx = __uint_as_float(hv << 16);
                float hy = __uint_as_float(hv & 0xffff0000u);
                denom += wj;
                accx += wj * hx; accy += wj * hy;
            }
        } else {
            for (int j = 0; j < m; ++j) {
                int   sj = __shfl(s, j);
                float wj = __shfl(w, (head << 4) | j);
                unsigned int hv = ((const unsigned int*)(hb + (size_t)sj * 128))[lane];
                float hx = __uint_as_float(hv << 16);
                float hy = __uint_as_float(hv & 0xffff0000u);
                denom += wj;
                accx += wj * hx; accy += wj * hy;
            }
        }
    }
    const float inv = __frcp_rn(denom);
    float2 bv = ((const float2*)bias)[lane];
    ((float2*)(out + (size_t)n * 128))[lane] =
        make_float2(accx * inv + bv.x, accy * inv + bv.y);
}

extern "C" void kernel_launch(void* const* d_in, const int* in_sizes, int n_in,
                              void* d_out, int out_size, void* d_ws, size_t ws_size,
                              hipStream_t stream) {
    const float* x     = (const float*)d_in[0];
    const int*   ei    = (const int*)d_in[1];   // int64 ref -> delivered int32
    const float* W     = (const float*)d_in[2];
    const float* att_s = (const float*)d_in[3];
    const float* att_d = (const float*)d_in[4];
    const float* bias  = (const float*)d_in[5];
    float*       out   = (float*)d_out;
    char*        ws    = (char*)d_ws;

    // ws layout (bytes):
    // hb (bf16) 12.8MB | a_src 0.8MB | a_dst 0.8MB | off 50177*4 | csr 3.2MB |
    // bktdata 196*5120*4 = 4.01MB | bcnt 784B | bktoff 784B
    unsigned short* hb = (unsigned short*)(ws);
    float* a_src  = (float*)(ws + 12800000);
    float* a_dst  = (float*)(ws + 13600000);
    int*   off    = (int*)  (ws + 14400000);
    int*   csr    = (int*)  (ws + 14600768);
    unsigned int* bktdata = (unsigned int*)(ws + 17800768);
    int*   bcnt   = (int*)  (ws + 21814848);
    int*   bktoff = (int*)  (ws + 21815680);

    hipMemsetAsync(bcnt, 0, NBKT * sizeof(int), stream);
    gemm_k  <<<782,   256, 0, stream>>>(x, W, hb, att_s, att_d, a_src, a_dst);
    bin_k   <<<196,   256, 0, stream>>>(ei, bcnt, bktdata);
    bscan_k <<<1,     256, 0, stream>>>(bcnt, bktoff);
    sort_k  <<<196,   256, 0, stream>>>(bcnt, bktoff, bktdata, off, csr);
    gather_k<<<12500, 256, 0, stream>>>(off, csr, hb, a_src, a_dst, bias, out);
}